// Round 13
// baseline (160.863 us; speedup 1.0000x reference)
//
#include <hip/hip_runtime.h>

typedef _Float16 f16;
typedef _Float16 h8 __attribute__((ext_vector_type(8)));
typedef float f4 __attribute__((ext_vector_type(4)));

#define NLON 512
#define NLAT 256
#define NC   64
#define NM   256
#define NL   256
#define RTOT (NC*NLAT)   // 16384

// ---- workspace byte offsets ----
#define BO_FTR 0
#define BO_FTI (BO_FTR + 262144)
#define BO_GR  (BO_FTI + 262144)
#define BO_GI  (BO_GR  + 262144)
#define BO_WTR (BO_GI  + 262144)
#define BO_WTI (BO_WTR + 2097152)
#define BO_XFRE (BO_WTI + 2097152)   // f16 [m][c][k] — reused as XK [m][o][k]
#define BO_XFIM (BO_XFRE + 8388608)
#define BO_PRE  (BO_XFIM + 8388608)  // f16 P [l][m][c]
#define BO_PIM  (BO_PRE + 8388608)
#define BO_QRE  (BO_PIM + 8388608)   // f16 Q [l][m][o]
#define BO_QIM  (BO_QRE + 8388608)

__device__ inline f4 mfma16(h8 a, h8 b, f4 c) {
  return __builtin_amdgcn_mfma_f32_16x16x32_f16(a, b, c, 0, 0, 0);
}

// ---- tables: Ftr/Fti [m=256][n=512], Gr/Gi [n=512][m=256], all f16 ----
__global__ void k_tables_h(f16* __restrict__ Ftr, f16* __restrict__ Fti,
                           f16* __restrict__ Gr, f16* __restrict__ Gi) {
  int idx = blockIdx.x * blockDim.x + threadIdx.x;
  if (idx >= NLON * NM) return;
  const float step = 3.14159265358979323846f / 256.0f;
  {
    int m = idx >> 9, n = idx & 511;
    int t = (n * m) & (NLON - 1);
    float th = t * step;
    const float sc = 6.2831853071795864769f / 512.0f;
    Ftr[idx] = (f16)(sc * cosf(th));
    Fti[idx] = (f16)(-sc * sinf(th));
  }
  {
    int n = idx >> 8, m = idx & 255;
    int t = (n * m) & (NLON - 1);
    float th = t * step;
    float s = (m == 0) ? 1.0f : 2.0f;
    Gr[idx] = (f16)(s * cosf(th));
    Gi[idx] = (f16)(-s * sinf(th));
  }
}

// both weights: [i][o][l] f32 -> wT [l][o][i] f16 (z&1 selects re/im)
__global__ void k_permw2(const float* __restrict__ wr, const float* __restrict__ wi,
                         f16* __restrict__ wTr, f16* __restrict__ wTi) {
  __shared__ float tile[32][33];
  int z = blockIdx.z;
  int o = z >> 1;
  const float* w = (z & 1) ? wi : wr;
  f16* wT = (z & 1) ? wTi : wTr;
  int i0 = blockIdx.y * 32;
  int l0 = blockIdx.x * 32;
  int xx = threadIdx.x, yy = threadIdx.y;
  for (int j = 0; j < 32; j += 8)
    tile[yy + j][xx] = w[(size_t)(i0 + yy + j) * (NC * NL) + (size_t)o * NL + l0 + xx];
  __syncthreads();
  for (int j = 0; j < 32; j += 8)
    wT[(size_t)(l0 + yy + j) * (NC * NC) + (size_t)o * NC + i0 + xx] = (f16)tile[xx][yy + j];
}

// ---- S1: XF[m][r] = sum_n F[m][n]*x[r][n]; x fully LDS-staged; F direct-to-reg;
//      ZERO in-loop barriers; fused residual ----
__global__ __launch_bounds__(256) void k_s1(
    const float* __restrict__ x, const f16* __restrict__ Ftr,
    const f16* __restrict__ Fti, f16* __restrict__ XFre, f16* __restrict__ XFim,
    float* __restrict__ res) {
  __shared__ f16 Bx[64 * 520];  // x tile [r=64][n=512] pad->520 (66.5 KB)
  int t = threadIdx.x;
  int m0 = blockIdx.x * 128, r0 = blockIdx.y * 64;
  int lane = t & 63, w = t >> 6;
  int wm = (w >> 1) * 32, wn = (w & 1) * 32;
  int fr = lane & 15, kg = (lane >> 4) * 8;
  int srow = t >> 2, sc = (t & 3) * 16;
  const float* xrow = x + (size_t)(r0 + srow) * NLON;
  float* rrow = res + (size_t)(r0 + srow) * NLON;
  bool do_res = (blockIdx.x == 0);
#pragma unroll
  for (int rep = 0; rep < 8; ++rep) {
    int n = rep * 64 + sc;
    float4 v0 = *(const float4*)(xrow + n);
    float4 v1 = *(const float4*)(xrow + n + 4);
    float4 v2 = *(const float4*)(xrow + n + 8);
    float4 v3 = *(const float4*)(xrow + n + 12);
    if (do_res) {
      *(float4*)(rrow + n) = v0; *(float4*)(rrow + n + 4) = v1;
      *(float4*)(rrow + n + 8) = v2; *(float4*)(rrow + n + 12) = v3;
    }
    h8 h0 = {(f16)v0.x, (f16)v0.y, (f16)v0.z, (f16)v0.w,
             (f16)v1.x, (f16)v1.y, (f16)v1.z, (f16)v1.w};
    h8 h1 = {(f16)v2.x, (f16)v2.y, (f16)v2.z, (f16)v2.w,
             (f16)v3.x, (f16)v3.y, (f16)v3.z, (f16)v3.w};
    *(h8*)&Bx[srow * 520 + n] = h0;
    *(h8*)&Bx[srow * 520 + n + 8] = h1;
  }
  __syncthreads();  // the only barrier
  f4 aR[4][2] = {}, aI[4][2] = {};
  const f16* Fr0 = Ftr + (size_t)m0 * NLON;
  const f16* Fi0 = Fti + (size_t)m0 * NLON;
#pragma unroll 4
  for (int n0 = 0; n0 < NLON; n0 += 32) {
    h8 b0 = *(const h8*)&Bx[(wn + fr) * 520 + n0 + kg];
    h8 b1 = *(const h8*)&Bx[(wn + 16 + fr) * 520 + n0 + kg];
#pragma unroll
    for (int im = 0; im < 4; ++im) {
      int mrow = wm + (im >> 1) * 64 + (im & 1) * 16 + fr;
      h8 a = *(const h8*)(Fr0 + (size_t)mrow * NLON + n0 + kg);
      h8 c = *(const h8*)(Fi0 + (size_t)mrow * NLON + n0 + kg);
      aR[im][0] = mfma16(a, b0, aR[im][0]); aR[im][1] = mfma16(a, b1, aR[im][1]);
      aI[im][0] = mfma16(c, b0, aI[im][0]); aI[im][1] = mfma16(c, b1, aI[im][1]);
    }
  }
  int drow = (lane >> 4) * 4, dcol = lane & 15;
#pragma unroll
  for (int im = 0; im < 4; ++im)
#pragma unroll
    for (int j = 0; j < 2; ++j)
#pragma unroll
      for (int b = 0; b < 4; ++b) {
        int mg = m0 + wm + (im >> 1) * 64 + (im & 1) * 16 + drow + b;
        size_t o = (size_t)mg * RTOT + r0 + wn + j * 16 + dcol;
        XFre[o] = (f16)aR[im][j][b];
        XFim[o] = (f16)aI[im][j][b];
      }
}

// ---- S2 (per m): C[c][l] = sum_k XF[m][c][k]*shtw[m][l][k]; XF fully staged;
//      shtw direct-to-reg; writes P[l][m][c] ----
__global__ __launch_bounds__(256) void k_s2(
    const f16* __restrict__ XFre, const f16* __restrict__ XFim,
    const float* __restrict__ shtw, f16* __restrict__ Pre, f16* __restrict__ Pim) {
  int m = blockIdx.y;
  int l0 = blockIdx.x * 64;
  int t = threadIdx.x;
  if (l0 + 64 <= m) return;  // never read downstream
  __shared__ f16 SH[2 * 64 * 264];  // Axr | Axi, [c=64][k=256] pad->264 (66 KB)
  f16* Axr = SH;
  f16* Axi = SH + 64 * 264;
  int lane = t & 63, w = t >> 6;
  int wm = (w >> 1) * 32, wn = (w & 1) * 32;
  int fr = lane & 15, kg = (lane >> 4) * 8;
  const f16* Abr = XFre + (size_t)m * RTOT;
  const f16* Abi = XFim + (size_t)m * RTOT;
#pragma unroll
  for (int rep = 0; rep < 8; ++rep) {
    int f = rep * 256 + t;
    int row = f >> 5, c8 = (f & 31) * 8;
    *(h8*)&Axr[row * 264 + c8] = *(const h8*)(Abr + (size_t)row * NLAT + c8);
    *(h8*)&Axi[row * 264 + c8] = *(const h8*)(Abi + (size_t)row * NLAT + c8);
  }
  __syncthreads();
  const float* Bb = shtw + (size_t)m * (NL * NLAT);
  f4 aR[2][2] = {}, aI[2][2] = {};
#pragma unroll 2
  for (int k0 = 0; k0 < NLAT; k0 += 32) {
    h8 a0 = *(const h8*)&Axr[(wm + fr) * 264 + k0 + kg];
    h8 a1 = *(const h8*)&Axr[(wm + 16 + fr) * 264 + k0 + kg];
    h8 c0 = *(const h8*)&Axi[(wm + fr) * 264 + k0 + kg];
    h8 c1 = *(const h8*)&Axi[(wm + 16 + fr) * 264 + k0 + kg];
    const float* pb0 = Bb + (size_t)(l0 + wn + fr) * NLAT + k0 + kg;
    const float* pb1 = Bb + (size_t)(l0 + wn + 16 + fr) * NLAT + k0 + kg;
    float4 u0 = *(const float4*)pb0, u1 = *(const float4*)(pb0 + 4);
    float4 u2 = *(const float4*)pb1, u3 = *(const float4*)(pb1 + 4);
    h8 b0 = {(f16)u0.x, (f16)u0.y, (f16)u0.z, (f16)u0.w,
             (f16)u1.x, (f16)u1.y, (f16)u1.z, (f16)u1.w};
    h8 b1 = {(f16)u2.x, (f16)u2.y, (f16)u2.z, (f16)u2.w,
             (f16)u3.x, (f16)u3.y, (f16)u3.z, (f16)u3.w};
    aR[0][0] = mfma16(a0, b0, aR[0][0]); aR[0][1] = mfma16(a0, b1, aR[0][1]);
    aR[1][0] = mfma16(a1, b0, aR[1][0]); aR[1][1] = mfma16(a1, b1, aR[1][1]);
    aI[0][0] = mfma16(c0, b0, aI[0][0]); aI[0][1] = mfma16(c0, b1, aI[0][1]);
    aI[1][0] = mfma16(c1, b0, aI[1][0]); aI[1][1] = mfma16(c1, b1, aI[1][1]);
  }
  __syncthreads();  // before reusing SH for epilogue restage
  f16* Tr = SH;
  f16* Ti = SH + 4608;
  int drow = (lane >> 4) * 4, dcol = lane & 15;
#pragma unroll
  for (int i = 0; i < 2; ++i)
#pragma unroll
    for (int j = 0; j < 2; ++j)
#pragma unroll
      for (int b = 0; b < 4; ++b) {
        int c = wm + i * 16 + drow + b;
        int l = wn + j * 16 + dcol;
        Tr[l * 72 + c] = (f16)aR[i][j][b];
        Ti[l * 72 + c] = (f16)aI[i][j][b];
      }
  __syncthreads();
#pragma unroll
  for (int rep = 0; rep < 4; ++rep) {
    int f = rep * 256 + t;
    int buf = f >> 9, idx = f & 511;
    int ll = idx >> 3, c8 = (idx & 7) * 8;
    const f16* T = buf ? Ti : Tr;
    h8 v = *(const h8*)&T[ll * 72 + c8];
    f16* Pd = buf ? Pim : Pre;
    *(h8*)(Pd + (size_t)(l0 + ll) * RTOT + (size_t)m * 64 + c8) = v;
  }
}

// ---- S3 (per l): O[m][o] = sum_i P[l][m][i]*wT[l][o][i] (complex); out Q[l][m][o] ----
__global__ __launch_bounds__(256) void k_s3(
    const f16* __restrict__ Pre, const f16* __restrict__ Pim,
    const f16* __restrict__ wTr, const f16* __restrict__ wTi,
    f16* __restrict__ Qre, f16* __restrict__ Qim) {
  int l = blockIdx.y;
  int m0 = blockIdx.x * 64;
  int t = threadIdx.x;
  size_t obase = (size_t)l * RTOT + (size_t)m0 * 64;
  if (m0 > l) return;  // never read downstream
  __shared__ f16 SH[18432];
  f16* Ar = SH;
  f16* Ai = SH + 4608;
  f16* Br = SH + 9216;
  f16* Bi = SH + 13824;
  const f16* Pbr = Pre + (size_t)l * RTOT + (size_t)m0 * 64;
  const f16* Pbi = Pim + (size_t)l * RTOT + (size_t)m0 * 64;
  const f16* Wbr = wTr + (size_t)l * 4096;
  const f16* Wbi = wTi + (size_t)l * 4096;
#pragma unroll
  for (int rep = 0; rep < 2; ++rep) {
    int f = rep * 256 + t;
    int row = f >> 3, c8 = (f & 7) * 8;
    *(h8*)&Ar[row * 72 + c8] = *(const h8*)(Pbr + (size_t)row * 64 + c8);
    *(h8*)&Ai[row * 72 + c8] = *(const h8*)(Pbi + (size_t)row * 64 + c8);
    *(h8*)&Br[row * 72 + c8] = *(const h8*)(Wbr + (size_t)f * 8);
    *(h8*)&Bi[row * 72 + c8] = *(const h8*)(Wbi + (size_t)f * 8);
  }
  __syncthreads();
  int lane = t & 63, w = t >> 6;
  int wm = (w >> 1) * 32, wn = (w & 1) * 32;
  int fr = lane & 15, kg = (lane >> 4) * 8;
  f4 RR[2][2] = {}, II[2][2] = {}, RI[2][2] = {}, IR[2][2] = {};
#pragma unroll
  for (int ks = 0; ks < 64; ks += 32) {
    h8 a0 = *(h8*)&Ar[(wm + fr) * 72 + ks + kg];
    h8 a1 = *(h8*)&Ar[(wm + 16 + fr) * 72 + ks + kg];
    h8 c0 = *(h8*)&Ai[(wm + fr) * 72 + ks + kg];
    h8 c1 = *(h8*)&Ai[(wm + 16 + fr) * 72 + ks + kg];
    h8 b0 = *(h8*)&Br[(wn + fr) * 72 + ks + kg];
    h8 b1 = *(h8*)&Br[(wn + 16 + fr) * 72 + ks + kg];
    h8 d0 = *(h8*)&Bi[(wn + fr) * 72 + ks + kg];
    h8 d1 = *(h8*)&Bi[(wn + 16 + fr) * 72 + ks + kg];
    RR[0][0] = mfma16(a0, b0, RR[0][0]); RR[0][1] = mfma16(a0, b1, RR[0][1]);
    RR[1][0] = mfma16(a1, b0, RR[1][0]); RR[1][1] = mfma16(a1, b1, RR[1][1]);
    II[0][0] = mfma16(c0, d0, II[0][0]); II[0][1] = mfma16(c0, d1, II[0][1]);
    II[1][0] = mfma16(c1, d0, II[1][0]); II[1][1] = mfma16(c1, d1, II[1][1]);
    RI[0][0] = mfma16(a0, d0, RI[0][0]); RI[0][1] = mfma16(a0, d1, RI[0][1]);
    RI[1][0] = mfma16(a1, d0, RI[1][0]); RI[1][1] = mfma16(a1, d1, RI[1][1]);
    IR[0][0] = mfma16(c0, b0, IR[0][0]); IR[0][1] = mfma16(c0, b1, IR[0][1]);
    IR[1][0] = mfma16(c1, b0, IR[1][0]); IR[1][1] = mfma16(c1, b1, IR[1][1]);
  }
  __syncthreads();
  f16* Tr = SH;
  f16* Ti = SH + 4608;
  int drow = (lane >> 4) * 4, dcol = lane & 15;
#pragma unroll
  for (int i = 0; i < 2; ++i)
#pragma unroll
    for (int j = 0; j < 2; ++j)
#pragma unroll
      for (int b = 0; b < 4; ++b) {
        int mm = wm + i * 16 + drow + b;
        int oo = wn + j * 16 + dcol;
        Tr[mm * 72 + oo] = (f16)(RR[i][j][b] - II[i][j][b]);
        Ti[mm * 72 + oo] = (f16)(RI[i][j][b] + IR[i][j][b]);
      }
  __syncthreads();
#pragma unroll
  for (int rep = 0; rep < 4; ++rep) {
    int f = rep * 256 + t;
    int buf = f >> 9, idx = f & 511;
    int mm = idx >> 3, o8 = (idx & 7) * 8;
    const f16* T = buf ? Ti : Tr;
    h8 v = *(const h8*)&T[mm * 72 + o8];
    f16* Qd = buf ? Qim : Qre;
    *(h8*)(Qd + obase + (size_t)mm * 64 + o8) = v;
  }
}

// ---- S4 (per m): XK[m][o][k] = sum_l Q[l][m][o]*pct[m][l][k]; k-tile 128 ----
__global__ __launch_bounds__(256) void k_s4(
    const f16* __restrict__ Qre, const f16* __restrict__ Qim,
    const float* __restrict__ pct, f16* __restrict__ XKre, f16* __restrict__ XKim) {
  __shared__ f16 As[32 * 66], Ais[32 * 66], Bs0[32 * 66], Bs1[32 * 66];
  int m = blockIdx.y;
  int k0b = blockIdx.x * 128;
  int t = threadIdx.x;
  int lane = t & 63, w = t >> 6;
  int wm = (w >> 1) * 32, wn = (w & 1) * 32;
  int fr = lane & 15, kg = (lane >> 4) * 8;
  int lr = t >> 3, c8 = (t & 7) * 8;
  const float* Bb = pct + (size_t)m * (NL * NLAT);
  f4 aR[2][4] = {}, aI[2][4] = {};
  int lstart = m & ~31;
  for (int l0 = lstart; l0 < NL; l0 += 32) {
    *(h8*)&As[lr * 66 + c8]  = *(const h8*)(Qre + (size_t)(l0 + lr) * RTOT + (size_t)m * 64 + c8);
    *(h8*)&Ais[lr * 66 + c8] = *(const h8*)(Qim + (size_t)(l0 + lr) * RTOT + (size_t)m * 64 + c8);
    const float* pb = Bb + (size_t)(l0 + lr) * NLAT + k0b + c8;
    {
      float4 v0 = *(const float4*)pb;
      float4 v1 = *(const float4*)(pb + 4);
      h8 hb = {(f16)v0.x, (f16)v0.y, (f16)v0.z, (f16)v0.w,
               (f16)v1.x, (f16)v1.y, (f16)v1.z, (f16)v1.w};
      *(h8*)&Bs0[lr * 66 + c8] = hb;
    }
    {
      float4 v0 = *(const float4*)(pb + 64);
      float4 v1 = *(const float4*)(pb + 68);
      h8 hb = {(f16)v0.x, (f16)v0.y, (f16)v0.z, (f16)v0.w,
               (f16)v1.x, (f16)v1.y, (f16)v1.z, (f16)v1.w};
      *(h8*)&Bs1[lr * 66 + c8] = hb;
    }
    __syncthreads();
    h8 a0, a1, c0, c1, b0, b1, b2, b3;
#pragma unroll
    for (int e = 0; e < 8; ++e) {
      int row = (kg + e) * 66;
      a0[e] = As[row + wm + fr];
      a1[e] = As[row + wm + 16 + fr];
      c0[e] = Ais[row + wm + fr];
      c1[e] = Ais[row + wm + 16 + fr];
      b0[e] = Bs0[row + wn + fr];
      b1[e] = Bs0[row + wn + 16 + fr];
      b2[e] = Bs1[row + wn + fr];
      b3[e] = Bs1[row + wn + 16 + fr];
    }
    aR[0][0] = mfma16(a0, b0, aR[0][0]); aR[0][1] = mfma16(a0, b1, aR[0][1]);
    aR[0][2] = mfma16(a0, b2, aR[0][2]); aR[0][3] = mfma16(a0, b3, aR[0][3]);
    aR[1][0] = mfma16(a1, b0, aR[1][0]); aR[1][1] = mfma16(a1, b1, aR[1][1]);
    aR[1][2] = mfma16(a1, b2, aR[1][2]); aR[1][3] = mfma16(a1, b3, aR[1][3]);
    aI[0][0] = mfma16(c0, b0, aI[0][0]); aI[0][1] = mfma16(c0, b1, aI[0][1]);
    aI[0][2] = mfma16(c0, b2, aI[0][2]); aI[0][3] = mfma16(c0, b3, aI[0][3]);
    aI[1][0] = mfma16(c1, b0, aI[1][0]); aI[1][1] = mfma16(c1, b1, aI[1][1]);
    aI[1][2] = mfma16(c1, b2, aI[1][2]); aI[1][3] = mfma16(c1, b3, aI[1][3]);
    __syncthreads();
  }
  int drow = (lane >> 4) * 4, dcol = lane & 15;
#pragma unroll
  for (int i = 0; i < 2; ++i)
#pragma unroll
    for (int j = 0; j < 4; ++j)
#pragma unroll
      for (int b = 0; b < 4; ++b) {
        int orow = wm + i * 16 + drow + b;
        int kcol = k0b + (j >> 1) * 64 + (j & 1) * 16 + wn + dcol;
        size_t o = (size_t)m * RTOT + (size_t)orow * NLAT + kcol;
        XKre[o] = (f16)aR[i][j][b];
        XKim[o] = (f16)aI[i][j][b];
      }
}

// ---- S5: y[r][n] = sum_m XK[m][r]*G[n][m]; XK fully staged; G direct-to-reg ----
__global__ __launch_bounds__(256) void k_s5(
    const f16* __restrict__ XKre, const f16* __restrict__ XKim,
    const f16* __restrict__ Gr, const f16* __restrict__ Gi,
    float* __restrict__ y) {
  __shared__ f16 SH[2 * 256 * 66];  // Axr | Axi, [m=256][r=64] pad->66 (66 KB)
  f16* Axr = SH;
  f16* Axi = SH + 256 * 66;
  int t = threadIdx.x;
  int n0 = blockIdx.x * 128, r0 = blockIdx.y * 64;
  int lane = t & 63, w = t >> 6;
  int wm = (w >> 1) * 32, wn = (w & 1) * 32;
  int fr = lane & 15, kg = (lane >> 4) * 8;
#pragma unroll
  for (int rep = 0; rep < 8; ++rep) {
    int f = rep * 256 + t;
    int row = f >> 3, c8 = (f & 7) * 8;
    *(h8*)&Axr[row * 66 + c8] = *(const h8*)(XKre + (size_t)row * RTOT + r0 + c8);
    *(h8*)&Axi[row * 66 + c8] = *(const h8*)(XKim + (size_t)row * RTOT + r0 + c8);
  }
  __syncthreads();  // the only barrier
  f4 acc[2][4] = {};
#pragma unroll 2
  for (int m0 = 0; m0 < NM; m0 += 32) {
    h8 a0, a1, c0, c1;
#pragma unroll
    for (int e = 0; e < 8; ++e) {
      int row = (m0 + kg + e) * 66;
      a0[e] = Axr[row + wm + fr];
      a1[e] = Axr[row + wm + 16 + fr];
      c0[e] = Axi[row + wm + fr];
      c1[e] = Axi[row + wm + 16 + fr];
    }
#pragma unroll
    for (int j = 0; j < 4; ++j) {
      int nb = wn + (j & 1) * 16 + (j >> 1) * 64;
      h8 b = *(const h8*)(Gr + (size_t)(n0 + nb + fr) * NM + m0 + kg);
      h8 d = *(const h8*)(Gi + (size_t)(n0 + nb + fr) * NM + m0 + kg);
      acc[0][j] = mfma16(a0, b, acc[0][j]);
      acc[1][j] = mfma16(a1, b, acc[1][j]);
      acc[0][j] = mfma16(c0, d, acc[0][j]);
      acc[1][j] = mfma16(c1, d, acc[1][j]);
    }
  }
  int drow = (lane >> 4) * 4, dcol = lane & 15;
#pragma unroll
  for (int i = 0; i < 2; ++i)
#pragma unroll
    for (int j = 0; j < 4; ++j)
#pragma unroll
      for (int b = 0; b < 4; ++b) {
        int rg = r0 + wm + i * 16 + drow + b;
        int ng = n0 + wn + (j & 1) * 16 + (j >> 1) * 64 + dcol;
        y[(size_t)rg * NLON + ng] = acc[i][j][b];
      }
}

extern "C" void kernel_launch(void* const* d_in, const int* in_sizes, int n_in,
                              void* d_out, int out_size, void* d_ws, size_t ws_size,
                              hipStream_t stream) {
  const float* x    = (const float*)d_in[0];
  const float* wgr  = (const float*)d_in[1];
  const float* wgi  = (const float*)d_in[2];
  const float* pct  = (const float*)d_in[3];
  const float* shtw = (const float*)d_in[4];
  float* out = (float*)d_out;
  char* ws = (char*)d_ws;

  f16* Ftr = (f16*)(ws + BO_FTR);
  f16* Fti = (f16*)(ws + BO_FTI);
  f16* Gr  = (f16*)(ws + BO_GR);
  f16* Gi  = (f16*)(ws + BO_GI);
  f16* wTr = (f16*)(ws + BO_WTR);
  f16* wTi = (f16*)(ws + BO_WTI);
  f16* XFre = (f16*)(ws + BO_XFRE);  // XF, later XK
  f16* XFim = (f16*)(ws + BO_XFIM);
  f16* Pre  = (f16*)(ws + BO_PRE);
  f16* Pim  = (f16*)(ws + BO_PIM);
  f16* Qre  = (f16*)(ws + BO_QRE);
  f16* Qim  = (f16*)(ws + BO_QIM);

  float* res = out + (size_t)NC * NLAT * NLON;

  hipLaunchKernelGGL(k_tables_h, dim3(512), dim3(256), 0, stream, Ftr, Fti, Gr, Gi);
  hipLaunchKernelGGL(k_permw2, dim3(8, 2, 128), dim3(32, 8), 0, stream, wgr, wgi, wTr, wTi);
  // S1: forward DFT, barrier-free main loop, fused residual
  hipLaunchKernelGGL(k_s1, dim3(2, 256), dim3(256), 0, stream, x, Ftr, Fti, XFre, XFim, res);
  // S2: forward Legendre, barrier-free main loop
  hipLaunchKernelGGL(k_s2, dim3(4, 256), dim3(256), 0, stream, XFre, XFim, shtw, Pre, Pim);
  // S3: per-l weight GEMM -> Q[l][m][o]
  hipLaunchKernelGGL(k_s3, dim3(4, 256), dim3(256), 0, stream, Pre, Pim, wTr, wTi, Qre, Qim);
  // S4: inverse Legendre -> XK[m][o][k]
  hipLaunchKernelGGL(k_s4, dim3(2, 256), dim3(256), 0, stream, Qre, Qim, pct, XFre, XFim);
  // S5: inverse DFT, barrier-free main loop
  hipLaunchKernelGGL(k_s5, dim3(4, 256), dim3(256), 0, stream, XFre, XFim, Gr, Gi, out);
}

// Round 14
// 112.689 us; speedup vs baseline: 1.4275x; 1.4275x over previous
//
#include <hip/hip_runtime.h>

typedef _Float16 f16;
typedef _Float16 h8 __attribute__((ext_vector_type(8)));
typedef float f4 __attribute__((ext_vector_type(4)));

#define NLON 512
#define NLAT 256
#define NC   64
#define NM   256
#define NL   256
#define RTOT (NC*NLAT)   // 16384

// ---- workspace byte offsets ----
#define BO_FTR 0
#define BO_FTI (BO_FTR + 262144)
#define BO_GR  (BO_FTI + 262144)
#define BO_GI  (BO_GR  + 262144)
#define BO_WTR (BO_GI  + 262144)
#define BO_WTI (BO_WTR + 2097152)
#define BO_XFRE (BO_WTI + 2097152)   // f16 [m][c][k] — reused as XK [m][o][k]
#define BO_XFIM (BO_XFRE + 8388608)
#define BO_PRE  (BO_XFIM + 8388608)  // f16 P [l][m][c]
#define BO_PIM  (BO_PRE + 8388608)
#define BO_QRE  (BO_PIM + 8388608)   // f16 Q [l][m][o]
#define BO_QIM  (BO_QRE + 8388608)

__device__ inline f4 mfma16(h8 a, h8 b, f4 c) {
  return __builtin_amdgcn_mfma_f32_16x16x32_f16(a, b, c, 0, 0, 0);
}

// ---- prep: tables (blocks 0..511) + weight permute (blocks 512..2559) ----
__global__ __launch_bounds__(256) void k_prep(
    f16* __restrict__ Ftr, f16* __restrict__ Fti,
    f16* __restrict__ Gr, f16* __restrict__ Gi,
    const float* __restrict__ wr, const float* __restrict__ wi,
    f16* __restrict__ wTr, f16* __restrict__ wTi) {
  int t = threadIdx.x;
  int bid = blockIdx.x;
  if (bid < 512) {
    int idx = bid * 256 + t;
    const float step = 3.14159265358979323846f / 256.0f;
    {
      int m = idx >> 9, n = idx & 511;
      int tt = (n * m) & (NLON - 1);
      float th = tt * step;
      const float sc = 6.2831853071795864769f / 512.0f;
      Ftr[idx] = (f16)(sc * cosf(th));
      Fti[idx] = (f16)(-sc * sinf(th));
    }
    {
      int n = idx >> 8, m = idx & 255;
      int tt = (n * m) & (NLON - 1);
      float th = tt * step;
      float s = (m == 0) ? 1.0f : 2.0f;
      Gr[idx] = (f16)(s * cosf(th));
      Gi[idx] = (f16)(-s * sinf(th));
    }
    return;
  }
  // weight permute: w [i][o][l] f32 -> wT [l][o][i] f16
  __shared__ float tile[32][33];
  int b = bid - 512;
  int z = b >> 4;
  int rem = b & 15;
  int i0 = (rem >> 3) * 32;
  int l0 = (rem & 7) * 32;
  int o = z >> 1;
  const float* w = (z & 1) ? wi : wr;
  f16* wT = (z & 1) ? wTi : wTr;
  int xx = t & 31, yy = t >> 5;
  for (int j = 0; j < 32; j += 8)
    tile[yy + j][xx] = w[(size_t)(i0 + yy + j) * (NC * NL) + (size_t)o * NL + l0 + xx];
  __syncthreads();
  for (int j = 0; j < 32; j += 8)
    wT[(size_t)(l0 + yy + j) * (NC * NC) + (size_t)o * NC + i0 + xx] = (f16)tile[xx][yy + j];
}

// ---- S1: XF[m][r] = sum_n F[m][n]*x[r][n]; m-tile 128; fused residual (r5 form) ----
__global__ __launch_bounds__(256) void k_s1(
    const float* __restrict__ x, const f16* __restrict__ Ftr,
    const f16* __restrict__ Fti, f16* __restrict__ XFre, f16* __restrict__ XFim,
    float* __restrict__ res) {
  __shared__ f16 Ar[128 * 40], Ai[128 * 40], Bx[64 * 40];
  int t = threadIdx.x;
  int m0 = blockIdx.x * 128, r0 = blockIdx.y * 64;
  int lane = t & 63, w = t >> 6;
  int wm = (w >> 1) * 32, wn = (w & 1) * 32;
  int fr = lane & 15, kg = (lane >> 4) * 8;
  int srow = t >> 2, skc = (t & 3) * 8;
  f4 aR[4][2] = {}, aI[4][2] = {};
  for (int n0 = 0; n0 < NLON; n0 += 32) {
#pragma unroll
    for (int rep = 0; rep < 2; ++rep) {
      int f = rep * 256 + t;
      int row = f >> 2, c8 = (f & 3) * 8;
      *(h8*)&Ar[row * 40 + c8] = *(const h8*)(Ftr + (size_t)(m0 + row) * NLON + n0 + c8);
      *(h8*)&Ai[row * 40 + c8] = *(const h8*)(Fti + (size_t)(m0 + row) * NLON + n0 + c8);
    }
    const float* px = x + (size_t)(r0 + srow) * NLON + n0 + skc;
    float4 v0 = *(const float4*)px;
    float4 v1 = *(const float4*)(px + 4);
    if (blockIdx.x == 0) {  // residual passthrough (measured free in-loop)
      float* pr = res + (size_t)(r0 + srow) * NLON + n0 + skc;
      *(float4*)pr = v0;
      *(float4*)(pr + 4) = v1;
    }
    h8 hx = {(f16)v0.x, (f16)v0.y, (f16)v0.z, (f16)v0.w,
             (f16)v1.x, (f16)v1.y, (f16)v1.z, (f16)v1.w};
    *(h8*)&Bx[srow * 40 + skc] = hx;
    __syncthreads();
    h8 b0 = *(h8*)&Bx[(wn + fr) * 40 + kg];
    h8 b1 = *(h8*)&Bx[(wn + 16 + fr) * 40 + kg];
#pragma unroll
    for (int im = 0; im < 4; ++im) {
      int mrow = wm + (im >> 1) * 64 + (im & 1) * 16 + fr;
      h8 a = *(h8*)&Ar[mrow * 40 + kg];
      h8 c = *(h8*)&Ai[mrow * 40 + kg];
      aR[im][0] = mfma16(a, b0, aR[im][0]); aR[im][1] = mfma16(a, b1, aR[im][1]);
      aI[im][0] = mfma16(c, b0, aI[im][0]); aI[im][1] = mfma16(c, b1, aI[im][1]);
    }
    __syncthreads();
  }
  int drow = (lane >> 4) * 4, dcol = lane & 15;
#pragma unroll
  for (int im = 0; im < 4; ++im)
#pragma unroll
    for (int j = 0; j < 2; ++j)
#pragma unroll
      for (int b = 0; b < 4; ++b) {
        int mg = m0 + wm + (im >> 1) * 64 + (im & 1) * 16 + drow + b;
        size_t o = (size_t)mg * RTOT + r0 + wn + j * 16 + dcol;
        XFre[o] = (f16)aR[im][j][b];
        XFim[o] = (f16)aI[im][j][b];
      }
}

// ---- S2 (per m): C[c][l] = sum_k XF[m][c][k]*shtw[m][l][k]; writes P[l][m][c] ----
__global__ __launch_bounds__(256) void k_s2(
    const f16* __restrict__ XFre, const f16* __restrict__ XFim,
    const float* __restrict__ shtw, f16* __restrict__ Pre, f16* __restrict__ Pim) {
  int m = blockIdx.y;
  int l0 = blockIdx.x * 64;
  int t = threadIdx.x;
  if (l0 + 64 <= m) return;  // tile never read downstream (s3 reads only m0 <= l)
  __shared__ f16 SH[9216];
  f16* Ar = SH;             // [64][40] rows=c
  f16* Ai = SH + 2560;
  f16* Bs = SH + 5120;      // [64][40] rows=l
  int lane = t & 63, w = t >> 6;
  int wm = (w >> 1) * 32, wn = (w & 1) * 32;
  int fr = lane & 15, kg = (lane >> 4) * 8;
  int srow = t >> 2, skc = (t & 3) * 8;
  const f16* Abr = XFre + (size_t)m * RTOT;
  const f16* Abi = XFim + (size_t)m * RTOT;
  const float* Bb = shtw + (size_t)m * (NL * NLAT);
  f4 aR[2][2] = {}, aI[2][2] = {};
  for (int k0 = 0; k0 < NLAT; k0 += 32) {
    *(h8*)&Ar[srow * 40 + skc] = *(const h8*)(Abr + (size_t)srow * NLAT + k0 + skc);
    *(h8*)&Ai[srow * 40 + skc] = *(const h8*)(Abi + (size_t)srow * NLAT + k0 + skc);
    const float* pb = Bb + (size_t)(l0 + srow) * NLAT + k0 + skc;
    float4 v0 = *(const float4*)pb;
    float4 v1 = *(const float4*)(pb + 4);
    h8 hb = {(f16)v0.x, (f16)v0.y, (f16)v0.z, (f16)v0.w,
             (f16)v1.x, (f16)v1.y, (f16)v1.z, (f16)v1.w};
    *(h8*)&Bs[srow * 40 + skc] = hb;
    __syncthreads();
    h8 a0 = *(h8*)&Ar[(wm + fr) * 40 + kg],      a1 = *(h8*)&Ar[(wm + 16 + fr) * 40 + kg];
    h8 c0 = *(h8*)&Ai[(wm + fr) * 40 + kg],      c1 = *(h8*)&Ai[(wm + 16 + fr) * 40 + kg];
    h8 b0 = *(h8*)&Bs[(wn + fr) * 40 + kg],      b1 = *(h8*)&Bs[(wn + 16 + fr) * 40 + kg];
    aR[0][0] = mfma16(a0, b0, aR[0][0]); aR[0][1] = mfma16(a0, b1, aR[0][1]);
    aR[1][0] = mfma16(a1, b0, aR[1][0]); aR[1][1] = mfma16(a1, b1, aR[1][1]);
    aI[0][0] = mfma16(c0, b0, aI[0][0]); aI[0][1] = mfma16(c0, b1, aI[0][1]);
    aI[1][0] = mfma16(c1, b0, aI[1][0]); aI[1][1] = mfma16(c1, b1, aI[1][1]);
    __syncthreads();
  }
  // restage to [l][c] then coalesced h8 writes to P[l][m][c]
  f16* Tr = SH;
  f16* Ti = SH + 4608;
  int drow = (lane >> 4) * 4, dcol = lane & 15;
#pragma unroll
  for (int i = 0; i < 2; ++i)
#pragma unroll
    for (int j = 0; j < 2; ++j)
#pragma unroll
      for (int b = 0; b < 4; ++b) {
        int c = wm + i * 16 + drow + b;
        int l = wn + j * 16 + dcol;
        Tr[l * 72 + c] = (f16)aR[i][j][b];
        Ti[l * 72 + c] = (f16)aI[i][j][b];
      }
  __syncthreads();
#pragma unroll
  for (int rep = 0; rep < 4; ++rep) {
    int f = rep * 256 + t;
    int buf = f >> 9, idx = f & 511;
    int ll = idx >> 3, c8 = (idx & 7) * 8;
    const f16* T = buf ? Ti : Tr;
    h8 v = *(const h8*)&T[ll * 72 + c8];
    f16* Pd = buf ? Pim : Pre;
    *(h8*)(Pd + (size_t)(l0 + ll) * RTOT + (size_t)m * 64 + c8) = v;
  }
}

// ---- S3 (per l): O[m][o] = sum_i P[l][m][i]*wT[l][o][i] (complex); out Q[l][m][o] ----
__global__ __launch_bounds__(256) void k_s3(
    const f16* __restrict__ Pre, const f16* __restrict__ Pim,
    const f16* __restrict__ wTr, const f16* __restrict__ wTi,
    f16* __restrict__ Qre, f16* __restrict__ Qim) {
  int l = blockIdx.y;
  int m0 = blockIdx.x * 64;
  int t = threadIdx.x;
  size_t obase = (size_t)l * RTOT + (size_t)m0 * 64;
  if (m0 > l) return;  // tile never read downstream (s4 reads only l >= m&~31)
  __shared__ f16 SH[18432];
  f16* Ar = SH;
  f16* Ai = SH + 4608;
  f16* Br = SH + 9216;
  f16* Bi = SH + 13824;
  const f16* Pbr = Pre + (size_t)l * RTOT + (size_t)m0 * 64;
  const f16* Pbi = Pim + (size_t)l * RTOT + (size_t)m0 * 64;
  const f16* Wbr = wTr + (size_t)l * 4096;
  const f16* Wbi = wTi + (size_t)l * 4096;
#pragma unroll
  for (int rep = 0; rep < 2; ++rep) {
    int f = rep * 256 + t;
    int row = f >> 3, c8 = (f & 7) * 8;
    *(h8*)&Ar[row * 72 + c8] = *(const h8*)(Pbr + (size_t)row * 64 + c8);
    *(h8*)&Ai[row * 72 + c8] = *(const h8*)(Pbi + (size_t)row * 64 + c8);
    *(h8*)&Br[row * 72 + c8] = *(const h8*)(Wbr + (size_t)f * 8);
    *(h8*)&Bi[row * 72 + c8] = *(const h8*)(Wbi + (size_t)f * 8);
  }
  __syncthreads();
  int lane = t & 63, w = t >> 6;
  int wm = (w >> 1) * 32, wn = (w & 1) * 32;
  int fr = lane & 15, kg = (lane >> 4) * 8;
  f4 RR[2][2] = {}, II[2][2] = {}, RI[2][2] = {}, IR[2][2] = {};
#pragma unroll
  for (int ks = 0; ks < 64; ks += 32) {
    h8 a0 = *(h8*)&Ar[(wm + fr) * 72 + ks + kg];
    h8 a1 = *(h8*)&Ar[(wm + 16 + fr) * 72 + ks + kg];
    h8 c0 = *(h8*)&Ai[(wm + fr) * 72 + ks + kg];
    h8 c1 = *(h8*)&Ai[(wm + 16 + fr) * 72 + ks + kg];
    h8 b0 = *(h8*)&Br[(wn + fr) * 72 + ks + kg];
    h8 b1 = *(h8*)&Br[(wn + 16 + fr) * 72 + ks + kg];
    h8 d0 = *(h8*)&Bi[(wn + fr) * 72 + ks + kg];
    h8 d1 = *(h8*)&Bi[(wn + 16 + fr) * 72 + ks + kg];
    RR[0][0] = mfma16(a0, b0, RR[0][0]); RR[0][1] = mfma16(a0, b1, RR[0][1]);
    RR[1][0] = mfma16(a1, b0, RR[1][0]); RR[1][1] = mfma16(a1, b1, RR[1][1]);
    II[0][0] = mfma16(c0, d0, II[0][0]); II[0][1] = mfma16(c0, d1, II[0][1]);
    II[1][0] = mfma16(c1, d0, II[1][0]); II[1][1] = mfma16(c1, d1, II[1][1]);
    RI[0][0] = mfma16(a0, d0, RI[0][0]); RI[0][1] = mfma16(a0, d1, RI[0][1]);
    RI[1][0] = mfma16(a1, d0, RI[1][0]); RI[1][1] = mfma16(a1, d1, RI[1][1]);
    IR[0][0] = mfma16(c0, b0, IR[0][0]); IR[0][1] = mfma16(c0, b1, IR[0][1]);
    IR[1][0] = mfma16(c1, b0, IR[1][0]); IR[1][1] = mfma16(c1, b1, IR[1][1]);
  }
  __syncthreads();
  f16* Tr = SH;
  f16* Ti = SH + 4608;
  int drow = (lane >> 4) * 4, dcol = lane & 15;
#pragma unroll
  for (int i = 0; i < 2; ++i)
#pragma unroll
    for (int j = 0; j < 2; ++j)
#pragma unroll
      for (int b = 0; b < 4; ++b) {
        int mm = wm + i * 16 + drow + b;
        int oo = wn + j * 16 + dcol;
        Tr[mm * 72 + oo] = (f16)(RR[i][j][b] - II[i][j][b]);
        Ti[mm * 72 + oo] = (f16)(RI[i][j][b] + IR[i][j][b]);
      }
  __syncthreads();
#pragma unroll
  for (int rep = 0; rep < 4; ++rep) {
    int f = rep * 256 + t;
    int buf = f >> 9, idx = f & 511;
    int mm = idx >> 3, o8 = (idx & 7) * 8;
    const f16* T = buf ? Ti : Tr;
    h8 v = *(const h8*)&T[mm * 72 + o8];
    f16* Qd = buf ? Qim : Qre;
    *(h8*)(Qd + obase + (size_t)mm * 64 + o8) = v;
  }
}

// ---- S4 (per m): XK[m][o][k] = sum_l Q[l][m][o]*pct[m][l][k]; k-tile 128 ----
__global__ __launch_bounds__(256) void k_s4(
    const f16* __restrict__ Qre, const f16* __restrict__ Qim,
    const float* __restrict__ pct, f16* __restrict__ XKre, f16* __restrict__ XKim) {
  __shared__ f16 As[32 * 66], Ais[32 * 66], Bs0[32 * 66], Bs1[32 * 66];
  int m = blockIdx.y;
  int k0b = blockIdx.x * 128;
  int t = threadIdx.x;
  int lane = t & 63, w = t >> 6;
  int wm = (w >> 1) * 32, wn = (w & 1) * 32;
  int fr = lane & 15, kg = (lane >> 4) * 8;
  int lr = t >> 3, c8 = (t & 7) * 8;
  const float* Bb = pct + (size_t)m * (NL * NLAT);
  f4 aR[2][4] = {}, aI[2][4] = {};
  int lstart = m & ~31;
  for (int l0 = lstart; l0 < NL; l0 += 32) {
    *(h8*)&As[lr * 66 + c8]  = *(const h8*)(Qre + (size_t)(l0 + lr) * RTOT + (size_t)m * 64 + c8);
    *(h8*)&Ais[lr * 66 + c8] = *(const h8*)(Qim + (size_t)(l0 + lr) * RTOT + (size_t)m * 64 + c8);
    const float* pb = Bb + (size_t)(l0 + lr) * NLAT + k0b + c8;
    {
      float4 v0 = *(const float4*)pb;
      float4 v1 = *(const float4*)(pb + 4);
      h8 hb = {(f16)v0.x, (f16)v0.y, (f16)v0.z, (f16)v0.w,
               (f16)v1.x, (f16)v1.y, (f16)v1.z, (f16)v1.w};
      *(h8*)&Bs0[lr * 66 + c8] = hb;
    }
    {
      float4 v0 = *(const float4*)(pb + 64);
      float4 v1 = *(const float4*)(pb + 68);
      h8 hb = {(f16)v0.x, (f16)v0.y, (f16)v0.z, (f16)v0.w,
               (f16)v1.x, (f16)v1.y, (f16)v1.z, (f16)v1.w};
      *(h8*)&Bs1[lr * 66 + c8] = hb;
    }
    __syncthreads();
    h8 a0, a1, c0, c1, b0, b1, b2, b3;
#pragma unroll
    for (int e = 0; e < 8; ++e) {
      int row = (kg + e) * 66;
      a0[e] = As[row + wm + fr];
      a1[e] = As[row + wm + 16 + fr];
      c0[e] = Ais[row + wm + fr];
      c1[e] = Ais[row + wm + 16 + fr];
      b0[e] = Bs0[row + wn + fr];
      b1[e] = Bs0[row + wn + 16 + fr];
      b2[e] = Bs1[row + wn + fr];
      b3[e] = Bs1[row + wn + 16 + fr];
    }
    aR[0][0] = mfma16(a0, b0, aR[0][0]); aR[0][1] = mfma16(a0, b1, aR[0][1]);
    aR[0][2] = mfma16(a0, b2, aR[0][2]); aR[0][3] = mfma16(a0, b3, aR[0][3]);
    aR[1][0] = mfma16(a1, b0, aR[1][0]); aR[1][1] = mfma16(a1, b1, aR[1][1]);
    aR[1][2] = mfma16(a1, b2, aR[1][2]); aR[1][3] = mfma16(a1, b3, aR[1][3]);
    aI[0][0] = mfma16(c0, b0, aI[0][0]); aI[0][1] = mfma16(c0, b1, aI[0][1]);
    aI[0][2] = mfma16(c0, b2, aI[0][2]); aI[0][3] = mfma16(c0, b3, aI[0][3]);
    aI[1][0] = mfma16(c1, b0, aI[1][0]); aI[1][1] = mfma16(c1, b1, aI[1][1]);
    aI[1][2] = mfma16(c1, b2, aI[1][2]); aI[1][3] = mfma16(c1, b3, aI[1][3]);
    __syncthreads();
  }
  int drow = (lane >> 4) * 4, dcol = lane & 15;
#pragma unroll
  for (int i = 0; i < 2; ++i)
#pragma unroll
    for (int j = 0; j < 4; ++j)
#pragma unroll
      for (int b = 0; b < 4; ++b) {
        int orow = wm + i * 16 + drow + b;
        int kcol = k0b + (j >> 1) * 64 + (j & 1) * 16 + wn + dcol;
        size_t o = (size_t)m * RTOT + (size_t)orow * NLAT + kcol;
        XKre[o] = (f16)aR[i][j][b];
        XKim[o] = (f16)aI[i][j][b];
      }
}

// ---- S5: y[r][n] = sum_m XK[m][r]*Gr[n][m] + XKim[m][r]*Gi[n][m]; n-tile 128 ----
__global__ __launch_bounds__(256) void k_s5(
    const f16* __restrict__ XKre, const f16* __restrict__ XKim,
    const f16* __restrict__ Gr, const f16* __restrict__ Gi,
    float* __restrict__ y) {
  __shared__ f16 Ar[32 * 66], Ai[32 * 66], Br[128 * 34], Bi[128 * 34];
  int t = threadIdx.x;
  int n0 = blockIdx.x * 128, r0 = blockIdx.y * 64;
  int lane = t & 63, w = t >> 6;
  int wm = (w >> 1) * 32, wn = (w & 1) * 32;
  int fr = lane & 15, kg = (lane >> 4) * 8;
  int mr = t >> 3, r8 = (t & 7) * 8;
  f4 acc[2][4] = {};
  for (int m0 = 0; m0 < NM; m0 += 32) {
    *(h8*)&Ar[mr * 66 + r8] = *(const h8*)(XKre + (size_t)(m0 + mr) * RTOT + r0 + r8);
    *(h8*)&Ai[mr * 66 + r8] = *(const h8*)(XKim + (size_t)(m0 + mr) * RTOT + r0 + r8);
#pragma unroll
    for (int rep = 0; rep < 2; ++rep) {
      int f = rep * 256 + t;
      int row = f >> 2, cc = (f & 3) * 8;
      *(h8*)&Br[row * 34 + cc] = *(const h8*)(Gr + (size_t)(n0 + row) * NM + m0 + cc);
      *(h8*)&Bi[row * 34 + cc] = *(const h8*)(Gi + (size_t)(n0 + row) * NM + m0 + cc);
    }
    __syncthreads();
    h8 a0, a1, c0, c1;
#pragma unroll
    for (int e = 0; e < 8; ++e) {
      int row = (kg + e) * 66;
      a0[e] = Ar[row + wm + fr];
      a1[e] = Ar[row + wm + 16 + fr];
      c0[e] = Ai[row + wm + fr];
      c1[e] = Ai[row + wm + 16 + fr];
    }
#pragma unroll
    for (int j = 0; j < 4; ++j) {
      int nb = wn + (j & 1) * 16 + (j >> 1) * 64;
      h8 b = *(h8*)&Br[(nb + fr) * 34 + kg];
      h8 d = *(h8*)&Bi[(nb + fr) * 34 + kg];
      acc[0][j] = mfma16(a0, b, acc[0][j]);
      acc[1][j] = mfma16(a1, b, acc[1][j]);
      acc[0][j] = mfma16(c0, d, acc[0][j]);
      acc[1][j] = mfma16(c1, d, acc[1][j]);
    }
    __syncthreads();
  }
  int drow = (lane >> 4) * 4, dcol = lane & 15;
#pragma unroll
  for (int i = 0; i < 2; ++i)
#pragma unroll
    for (int j = 0; j < 4; ++j)
#pragma unroll
      for (int b = 0; b < 4; ++b) {
        int rg = r0 + wm + i * 16 + drow + b;
        int ng = n0 + wn + (j & 1) * 16 + (j >> 1) * 64 + dcol;
        y[(size_t)rg * NLON + ng] = acc[i][j][b];
      }
}

extern "C" void kernel_launch(void* const* d_in, const int* in_sizes, int n_in,
                              void* d_out, int out_size, void* d_ws, size_t ws_size,
                              hipStream_t stream) {
  const float* x    = (const float*)d_in[0];
  const float* wgr  = (const float*)d_in[1];
  const float* wgi  = (const float*)d_in[2];
  const float* pct  = (const float*)d_in[3];
  const float* shtw = (const float*)d_in[4];
  float* out = (float*)d_out;
  char* ws = (char*)d_ws;

  f16* Ftr = (f16*)(ws + BO_FTR);
  f16* Fti = (f16*)(ws + BO_FTI);
  f16* Gr  = (f16*)(ws + BO_GR);
  f16* Gi  = (f16*)(ws + BO_GI);
  f16* wTr = (f16*)(ws + BO_WTR);
  f16* wTi = (f16*)(ws + BO_WTI);
  f16* XFre = (f16*)(ws + BO_XFRE);  // XF, later XK
  f16* XFim = (f16*)(ws + BO_XFIM);
  f16* Pre  = (f16*)(ws + BO_PRE);
  f16* Pim  = (f16*)(ws + BO_PIM);
  f16* Qre  = (f16*)(ws + BO_QRE);
  f16* Qim  = (f16*)(ws + BO_QIM);

  float* res = out + (size_t)NC * NLAT * NLON;

  // prep: tables + weight permute in one dispatch
  hipLaunchKernelGGL(k_prep, dim3(2560), dim3(256), 0, stream,
                     Ftr, Fti, Gr, Gi, wgr, wgi, wTr, wTi);
  // S1: forward DFT -> XF[m][c][k], fused residual
  hipLaunchKernelGGL(k_s1, dim3(2, 256), dim3(256), 0, stream, x, Ftr, Fti, XFre, XFim, res);
  // S2: forward Legendre -> P[l][m][c] (dead zero-fills removed)
  hipLaunchKernelGGL(k_s2, dim3(4, 256), dim3(256), 0, stream, XFre, XFim, shtw, Pre, Pim);
  // S3: per-l weight GEMM -> Q[l][m][o] (dead zero-fills removed)
  hipLaunchKernelGGL(k_s3, dim3(4, 256), dim3(256), 0, stream, Pre, Pim, wTr, wTi, Qre, Qim);
  // S4: inverse Legendre -> XK[m][o][k] (into XF region)
  hipLaunchKernelGGL(k_s4, dim3(2, 256), dim3(256), 0, stream, Qre, Qim, pct, XFre, XFim);
  // S5: inverse DFT -> y
  hipLaunchKernelGGL(k_s5, dim3(4, 256), dim3(256), 0, stream, XFre, XFim, Gr, Gi, out);
}